// Round 13
// baseline (301.054 us; speedup 1.0000x reference)
//
#include <hip/hip_runtime.h>
#include <hip/hip_bf16.h>
#include <math.h>

#define B_ 4
#define N_ 2048
#define F_ 128
#define H_ 4
#define NEG_BIG_F -9.0e15f
#define L2E 1.44269504088896f

typedef float v2 __attribute__((ext_vector_type(2)));
typedef float v4 __attribute__((ext_vector_type(4)));
typedef float f32x16 __attribute__((ext_vector_type(16)));
typedef short s16x8 __attribute__((ext_vector_type(8)));
typedef short s16x4 __attribute__((ext_vector_type(4)));
typedef unsigned u32x4 __attribute__((ext_vector_type(4)));
typedef unsigned u32x2 __attribute__((ext_vector_type(2)));

__device__ __forceinline__ float gelu_f(float x){
  return 0.5f*x*(1.0f+erff(x*0.70710678118654752f));
}
__device__ __forceinline__ float sigmoid_f(float x){
  return 1.0f/(1.0f+__expf(-x));
}
__device__ __forceinline__ short bfbits(float v){
  __hip_bfloat16 h = __float2bfloat16(v);
  short r; __builtin_memcpy(&r, &h, 2); return r;
}
// pack hi16(a), hi16(b) -> u32 (low short = hi16(a))
__device__ __forceinline__ unsigned packhi(float a, float b){
  return __builtin_amdgcn_perm(__float_as_uint(b), __float_as_uint(a), 0x07060302u);
}
__device__ __forceinline__ unsigned cvtpk_bf16(float a, float b){
  unsigned r;
  asm("v_cvt_pk_bf16_f32 %0, %1, %2" : "=v"(r) : "v"(a), "v"(b));
  return r;
}
__device__ __forceinline__ float exp2_f(float x){
  float r;
  asm("v_exp_f32 %0, %1" : "=v"(r) : "v"(x));
  return r;
}

// ---------------- Kernel 0: adjacency -> transposed bitmask maskT[b][word][n] ----------------
__global__ void __launch_bounds__(256) mask_kernel(
    const float* __restrict__ adj, unsigned* __restrict__ maskT)
{
  int v = blockIdx.x;            // b(4) x 64 tiles of 32 rows
  int b = v >> 6; int n0 = (v & 63) * 32;
  int t = threadIdx.x;
  int r = t >> 3, jg = t & 7;
  __shared__ unsigned mw[32][65];
  const float* arow = adj + (size_t)(b*N_ + n0 + r)*N_;
  for (int wq=0; wq<8; wq++){
    int wdi = jg + 8*wq;
    unsigned bits = 0;
    #pragma unroll
    for (int m=0;m<8;m++){
      v4 a = *(const v4*)(arow + wdi*32 + m*4);
      bits |= (a.x>0.f?1u:0u)<<(m*4);
      bits |= (a.y>0.f?1u:0u)<<(m*4+1);
      bits |= (a.z>0.f?1u:0u)<<(m*4+2);
      bits |= (a.w>0.f?1u:0u)<<(m*4+3);
    }
    mw[r][wdi] = bits;
  }
  __syncthreads();
  #pragma unroll
  for (int q=0;q<8;q++){
    int idx = t + q*256;
    int wdi = idx >> 5, rr = idx & 31;
    maskT[((size_t)b*64 + wdi)*N_ + n0 + rr] = mw[rr][wdi];
  }
}

// ---------------- Kernel 0b: merge mw1||gw1 into w1m[385][192] ----------------
__global__ void __launch_bounds__(192) w1m_kernel(
    const float* __restrict__ mw1, const float* __restrict__ gw1,
    float* __restrict__ w1m)
{
  int k = blockIdx.x;      // 0..384
  int c = threadIdx.x;     // 0..191
  w1m[(size_t)k*192 + c] = (c < 128) ? mw1[(size_t)k*128 + c]
                                     : gw1[(size_t)k*64 + (c-128)];
}

// ---------------- Kernel 1a: stage-1 MLP, K split across waves ----------------
__global__ void __launch_bounds__(256) mlp1_kernel(
    const float* __restrict__ deltas, const float* __restrict__ evt,
    const float* __restrict__ w1m,
    const float* __restrict__ mb1, const float* __restrict__ gb1,
    float* __restrict__ s1ws)
{
  int row0 = blockIdx.x * 8;       // 1024 blocks
  int t = threadIdx.x;
  int w = t >> 6, l = t & 63;
  int tcol = l & 31, rhalf = l >> 5;
  int c0 = tcol * 6;
  __shared__ float xs[8][392];
  __shared__ float pacc[4][8][192];

  for (int idx = t; idx < 8*385; idx += 256){
    int i = idx / 385;
    int k = idx - i*385;
    xs[i][k] = (k==0) ? deltas[row0+i] : evt[(size_t)(row0+i)*384 + (k-1)];
  }
  __syncthreads();

  int kstart = (w*385) >> 2, kend = ((w+1)*385) >> 2;
  float acc[4][6];
  #pragma unroll
  for (int r=0;r<4;r++)
    #pragma unroll
    for (int e=0;e<6;e++) acc[r][e] = 0.f;

  #pragma unroll 4
  for (int k=kstart; k<kend; k++){
    const float* wp = w1m + (size_t)k*192 + c0;
    v2 wa = *(const v2*)wp;
    v2 wb = *(const v2*)(wp+2);
    v2 wc = *(const v2*)(wp+4);
    #pragma unroll
    for (int r=0;r<4;r++){
      float x = xs[rhalf*4+r][k];
      acc[r][0] += x*wa.x; acc[r][1] += x*wa.y;
      acc[r][2] += x*wb.x; acc[r][3] += x*wb.y;
      acc[r][4] += x*wc.x; acc[r][5] += x*wc.y;
    }
  }
  #pragma unroll
  for (int r=0;r<4;r++){
    float* pp = &pacc[w][rhalf*4+r][c0];
    #pragma unroll
    for (int e=0;e<6;e++) pp[e] = acc[r][e];
  }
  __syncthreads();

  int row = t >> 5, cc0 = (t & 31) * 6;
  #pragma unroll
  for (int e=0;e<6;e++){
    int c = cc0 + e;
    float s = pacc[0][row][c] + pacc[1][row][c] + pacc[2][row][c] + pacc[3][row][c];
    s += (c < 128) ? mb1[c] : gb1[c-128];
    s1ws[(size_t)(row0+row)*192 + c] = gelu_f(s);
  }
}

// ---------------- Kernel 1b: stages 2+3, K split across waves ----------------
__global__ void __launch_bounds__(256) mlp2_kernel(
    const float* __restrict__ s1ws,
    const float* __restrict__ mw2, const float* __restrict__ mb2,
    const float* __restrict__ mw3, const float* __restrict__ mb3,
    const float* __restrict__ gw2, const float* __restrict__ gb2,
    float* __restrict__ h_out)
{
  int row0 = blockIdx.x * 8;       // 1024 blocks
  int t = threadIdx.x;
  int w = t >> 6, l = t & 63;
  int tcol = l & 31, rhalf = l >> 5;
  int c0 = tcol * 4;

  __shared__ float sm[1600 + 2048 + 2048 + 1024];
  float (*xs)[200] = (float(*)[200])sm;
  float* mpart = sm + 1600;       // [2][8][128]
  float* gpart = sm + 1600 + 2048;// [2][8][128]
  float* xs2   = sm + 1600 + 4096;// [8][128]
  float* p3    = sm + 1600;       // reuse mpart+gpart: [4][8][128]

  for (int idx = t; idx < 8*48; idx += 256){
    int i = idx / 48, c4 = idx - i*48;
    *(v4*)&xs[i][c4*4] = *(const v4*)(s1ws + (size_t)(row0+i)*192 + c4*4);
  }
  __syncthreads();

  // stage A
  {
    v4 acc[4];
    #pragma unroll
    for (int r=0;r<4;r++) acc[r] = (v4)0.f;
    if (w < 2){
      int ks2 = w*64;
      #pragma unroll 4
      for (int k=ks2; k<ks2+64; k++){
        v4 wv = *(const v4*)(mw2 + (size_t)k*128 + c0);
        #pragma unroll
        for (int r=0;r<4;r++) acc[r] += xs[rhalf*4+r][k]*wv;
      }
      #pragma unroll
      for (int r=0;r<4;r++)
        *(v4*)&mpart[((size_t)w*8 + rhalf*4+r)*128 + c0] = acc[r];
    } else {
      int ks2 = (w-2)*32;
      #pragma unroll 4
      for (int k=ks2; k<ks2+32; k++){
        v4 wv = *(const v4*)(gw2 + (size_t)k*128 + c0);
        #pragma unroll
        for (int r=0;r<4;r++) acc[r] += xs[rhalf*4+r][128+k]*wv;
      }
      #pragma unroll
      for (int r=0;r<4;r++)
        *(v4*)&gpart[((size_t)(w-2)*8 + rhalf*4+r)*128 + c0] = acc[r];
    }
  }
  __syncthreads();

  // stage B
  int row = t >> 5, cb = (t & 31) * 4;
  v4 gp;
  {
    v4 m2 = *(const v4*)&mpart[(size_t)row*128 + cb];
    m2 += *(const v4*)&mpart[(size_t)(8+row)*128 + cb];
    m2 += *(const v4*)(mb2 + cb);
    gp = *(const v4*)&gpart[(size_t)row*128 + cb];
    gp += *(const v4*)&gpart[(size_t)(8+row)*128 + cb];
    gp += *(const v4*)(gb2 + cb);
    v4 o;
    o.x = gelu_f(m2.x); o.y = gelu_f(m2.y); o.z = gelu_f(m2.z); o.w = gelu_f(m2.w);
    __syncthreads();               // mpart/gpart reads done before p3 overwrites
    *(v4*)&xs2[(size_t)row*128 + cb] = o;
  }
  __syncthreads();

  // stage C
  {
    v4 acc3[4];
    #pragma unroll
    for (int r=0;r<4;r++) acc3[r] = (v4)0.f;
    int kc = w*32;
    #pragma unroll 4
    for (int k=kc; k<kc+32; k++){
      v4 wv = *(const v4*)(mw3 + (size_t)k*128 + c0);
      #pragma unroll
      for (int r=0;r<4;r++) acc3[r] += xs2[(size_t)(rhalf*4+r)*128 + k]*wv;
    }
    #pragma unroll
    for (int r=0;r<4;r++)
      *(v4*)&p3[((size_t)w*8 + rhalf*4+r)*128 + c0] = acc3[r];
  }
  __syncthreads();

  {
    v4 s = *(const v4*)&p3[(size_t)row*128 + cb];
    s += *(const v4*)&p3[(size_t)(8+row)*128 + cb];
    s += *(const v4*)&p3[(size_t)(16+row)*128 + cb];
    s += *(const v4*)&p3[(size_t)(24+row)*128 + cb];
    s += *(const v4*)(mb3 + cb);
    v4 o;
    o.x = s.x * sigmoid_f(gp.x);
    o.y = s.y * sigmoid_f(gp.y);
    o.z = s.z * sigmoid_f(gp.z);
    o.w = s.w * sigmoid_f(gp.w);
    *(v4*)(h_out + (size_t)(row0+row)*F_ + cb) = o;
  }
}

// ---------------- Kernel 2: WhT (bf16 RNE) + partial s,t; 64 rows x 64 f per block ----------------
// grid = bh(16) x fhalf(2) x itile(32) = 1024 blocks -> 4 blocks/CU latency hiding.
// s,t partials per f-half written to sArrP/tArrP[fh][bh][n]; attn sums the halves.
__global__ void __launch_bounds__(256) wh_kernel(
    const float* __restrict__ h,
    const float* __restrict__ Wg_l,
    const float* __restrict__ asrc_l,
    const float* __restrict__ adst_l,
    short* __restrict__ WhT_hi,
    float* __restrict__ sArrP,
    float* __restrict__ tArrP)
{
  int v = blockIdx.x;
  int itile = v & 31;
  int fh = (v >> 5) & 1;
  int bh = v >> 6;
  int b = bh >> 2, hh = bh & 3;
  int n0 = itile * 64;
  int t = threadIdx.x;
  int fi = t & 15, ig = t >> 4;    // f0 = fi*4 (within 64-col half), i0 = ig*4
  int f0 = fi*4, i0 = ig*4;

  __shared__ float hT[128][72];
  for (int idx = t; idx < 64*128; idx += 256){
    int i = idx >> 7, k = idx & 127;
    hT[k][i] = h[(size_t)(b*N_ + n0 + i)*F_ + k];
  }
  __syncthreads();

  const float* W = Wg_l + (size_t)hh*F_*F_ + fh*64;
  v4 acc[4];                       // acc[r] = Wh[i0+r][fh*64+f0 .. +3]
  #pragma unroll
  for (int r=0;r<4;r++) acc[r] = (v4)0.f;
  #pragma unroll 4
  for (int k=0;k<F_;k++){
    v4 wv = *(const v4*)(W + (size_t)k*F_ + f0);
    v4 hv = *(const v4*)&hT[k][i0];
    acc[0] += hv.x*wv; acc[1] += hv.y*wv; acc[2] += hv.z*wv; acc[3] += hv.w*wv;
  }
  // transposed bf16 stores: WhT[bh][fh*64+f0+c][n0+i0 .. +3]
  #pragma unroll
  for (int c=0;c<4;c++){
    s16x4 hi4;
    #pragma unroll
    for (int e=0;e<4;e++) hi4[e] = bfbits(acc[e][c]);
    *(s16x4*)(WhT_hi + ((size_t)bh*F_ + fh*64 + f0 + c)*N_ + n0 + i0) = hi4;
  }
  // partial s,t over this half's 64 f: reduce across fi lanes (bits 0..3)
  v4 as4 = *(const v4*)(asrc_l + hh*F_ + fh*64 + f0);
  v4 ad4 = *(const v4*)(adst_l + hh*F_ + fh*64 + f0);
  float sv[4], tv[4];
  #pragma unroll
  for (int r=0;r<4;r++){
    sv[r] = acc[r].x*as4.x + acc[r].y*as4.y + acc[r].z*as4.z + acc[r].w*as4.w;
    tv[r] = acc[r].x*ad4.x + acc[r].y*ad4.y + acc[r].z*ad4.z + acc[r].w*ad4.w;
  }
  #pragma unroll
  for (int m=1;m<=8;m<<=1){
    #pragma unroll
    for (int r=0;r<4;r++){
      sv[r] += __shfl_xor(sv[r], m);
      tv[r] += __shfl_xor(tv[r], m);
    }
  }
  if (fi == 0){
    size_t base = (size_t)fh*16*N_ + (size_t)bh*N_ + n0 + i0;
    #pragma unroll
    for (int r=0;r<4;r++){
      sArrP[base + r] = sv[r];
      tArrP[base + r] = tv[r];
    }
  }
}

// ---------------- Kernel 3: MFMA masked-softmax + PV (P hi/lo split, Wh bf16-RNE) ----------------
#define WHS 44   // whT LDS stride in shorts (88B rows)
#define PBS 18   // pbuf row stride in u32 (72B rows: 2-way banks)
#define SOFF ((size_t)16*N_)   // f-half partial offset in sArrP/tArrP
__global__ void __launch_bounds__(512) attn_kernel(
    const unsigned* __restrict__ maskT,
    const short* __restrict__ WhT_hi,
    const float* __restrict__ sArrP,
    const float* __restrict__ tArrP,
    float* __restrict__ hpWS)
{
  int v = blockIdx.x;           // 512 blocks, XCD swizzle
  int seq = v >> 3, x8 = v & 7;
  int bh = (seq >> 5)*8 + x8;
  int itile = seq & 31;
  int b = bh >> 2;
  int n0 = itile * 64;
  int t = threadIdx.x;
  int w = t >> 6, l = t & 63;
  int lg = l >> 5, ln = l & 31;
  int ihalf = w & 1;
  int ks    = (w >> 1) & 1;
  int fhalf = w >> 2;

  __shared__ float t1L[N_];            // t * log2e   (reused as acc-reduce buffer)
  __shared__ float t2L[N_];            // 0.2 t * log2e
  __shared__ short whHiL[2][128*WHS];
  __shared__ unsigned pbufHi[2][2][32][PBS];
  __shared__ unsigned pbufLo[2][2][32][PBS];
  __shared__ float mxPart[8][64];
  __shared__ float mxL[64], amArgL[64], invL[64];
  __shared__ float lsP[2][4][32];

  const float* tp = tArrP + (size_t)bh*N_;
  #pragma unroll
  for (int q=0;q<4;q++){
    int x = t + q*512;
    float tvv = tp[x] + tp[x + SOFF];
    t1L[x] = tvv * L2E;
    t2L[x] = tvv * (0.2f*L2E);
  }

  // staging: 512 threads, 1 hi s16x8 each per tile
  s16x8 rh;
  int srow = t >> 2, sseg = t & 3;
  const short* gHi = WhT_hi + (size_t)bh*F_*N_;
  auto STAGE = [&](int jj0){
    size_t o = (size_t)srow*N_ + jj0 + sseg*8;
    rh = *(const s16x8*)(gHi + o);
  };
  auto WRITE = [&](int buf){
    int wo = srow*WHS + sseg*8;
    *(s16x4*)&whHiL[buf][wo]   = __builtin_shufflevector(rh,rh,0,1,2,3);
    *(s16x4*)&whHiL[buf][wo+4] = __builtin_shufflevector(rh,rh,4,5,6,7);
  };

  STAGE(0);
  int il = t & 63, qq = t >> 6;
  const float* sp = sArrP + (size_t)bh*N_;
  float s_il = sp[n0 + il] + sp[n0 + il + SOFF];
  float s1_il = s_il * L2E, s2_il = s_il * (0.2f*L2E);
  __syncthreads();   // t1L/t2L ready

  // phase 1: per-row max over active j, in exp2-scaled space
  float mx = NEG_BIG_F;
  const unsigned* mb1p = maskT + (size_t)b*64*N_ + n0;
  for (int wq=0; wq<8; wq++){
    int wdi = qq + wq*8;
    unsigned wd = mb1p[(size_t)wdi*N_ + il];
    while (wd){
      int k2 = __builtin_ctz(wd); wd &= wd - 1;
      float e = fmaxf(s1_il + t1L[wdi*32 + k2], s2_il + t2L[wdi*32 + k2]);
      mx = fmaxf(mx, e);
    }
  }
  mxPart[qq][il] = mx;
  WRITE(0);
  __syncthreads();
  if (t < 64){
    float m = mxPart[0][t];
    #pragma unroll
    for (int q=1;q<8;q++) m = fmaxf(m, mxPart[q][t]);
    bool am = (m <= -8.0e15f);
    mxL[t] = am ? 0.f : m;
    amArgL[t] = am ? 0.f : -1.0e30f;
  }
  __syncthreads();

  // lane constants (exp2-space, mx folded in)
  int irow = n0 + ihalf*32 + ln;
  float s_lane  = sp[irow] + sp[irow + SOFF];
  float mx_lane = mxL[ihalf*32 + ln];
  float amArg_lane = amArgL[ihalf*32 + ln];
  float Ac = s_lane*L2E - mx_lane;
  float Bc = s_lane*(0.2f*L2E) - mx_lane;
  const unsigned* mrow = maskT + (size_t)b*64*N_ + irow;

  f32x16 acc0, acc1;
  #pragma unroll
  for (int e2=0;e2<16;e2++){ acc0[e2]=0.f; acc1[e2]=0.f; }
  float lsum = 0.f;

  int jsub = ks*16 + fhalf*8 + lg*4;   // this lane's 4 p's
  int qidx = jsub >> 1;                 // u32 pair index (even)
  int sh0 = ks*16 + lg*8;               // this wave's A/B k-slot base

  unsigned mword = mrow[0];
  for (int c=0;c<64;c++){
    int j0 = c*32;
    int cb = c & 1;
    unsigned mword_nx = (c<63) ? mrow[(size_t)(c+1)*N_] : 0u;
    if (c<63) STAGE(j0 + 32);

    // ---- p-build: 4 values; arg = max(Ac+t1, Bc+t2); pe = exp2(sel) ----
    {
      v4 ta1 = *(const v4*)&t1L[j0 + jsub];
      v4 ta2 = *(const v4*)&t2L[j0 + jsub];
      unsigned mm = mword >> jsub;
      float a0 = fmaxf(Ac + ta1.x, Bc + ta2.x);
      float a1 = fmaxf(Ac + ta1.y, Bc + ta2.y);
      float a2 = fmaxf(Ac + ta1.z, Bc + ta2.z);
      float a3 = fmaxf(Ac + ta1.w, Bc + ta2.w);
      float pe0 = exp2_f((mm & 1u)      ? a0 : amArg_lane);
      float pe1 = exp2_f(((mm>>1) & 1u) ? a1 : amArg_lane);
      float pe2 = exp2_f(((mm>>2) & 1u) ? a2 : amArg_lane);
      float pe3 = exp2_f(((mm>>3) & 1u) ? a3 : amArg_lane);
      lsum += (pe0+pe1)+(pe2+pe3);
      u32x2 hiP, loP;
      hiP[0] = packhi(pe0, pe1);
      hiP[1] = packhi(pe2, pe3);
      float l0 = pe0 - __uint_as_float(__float_as_uint(pe0)&0xffff0000u);
      float l1 = pe1 - __uint_as_float(__float_as_uint(pe1)&0xffff0000u);
      float l2 = pe2 - __uint_as_float(__float_as_uint(pe2)&0xffff0000u);
      float l3 = pe3 - __uint_as_float(__float_as_uint(pe3)&0xffff0000u);
      loP[0] = cvtpk_bf16(l0, l1);
      loP[1] = cvtpk_bf16(l2, l3);
      *(u32x2*)&pbufHi[cb][ihalf][ln][qidx] = hiP;
      *(u32x2*)&pbufLo[cb][ihalf][ln][qidx] = loP;
    }
    __syncthreads();   // pbuf(c) + whL(c) ready; prev-iter reads all done

    // ---- MFMA: acc = (Phi + Plo) · Whhi ; 2 f-quadrant accs x 2 terms ----
    {
      int aq0 = ks*8 + lg*4;
      u32x2 ha2 = *(const u32x2*)&pbufHi[cb][ihalf][ln][aq0];
      u32x2 hb2 = *(const u32x2*)&pbufHi[cb][ihalf][ln][aq0+2];
      u32x2 la2 = *(const u32x2*)&pbufLo[cb][ihalf][ln][aq0];
      u32x2 lb2 = *(const u32x2*)&pbufLo[cb][ihalf][ln][aq0+2];
      u32x4 h4; h4[0]=ha2[0]; h4[1]=ha2[1]; h4[2]=hb2[0]; h4[3]=hb2[1];
      u32x4 l4; l4[0]=la2[0]; l4[1]=la2[1]; l4[2]=lb2[0]; l4[3]=lb2[1];
      s16x8 ahi = __builtin_bit_cast(s16x8, h4);
      s16x8 alo = __builtin_bit_cast(s16x8, l4);
      __builtin_amdgcn_s_setprio(1);
      #pragma unroll
      for (int aq=0; aq<2; aq++){
        int fr = fhalf*64 + aq*32 + ln;
        const short* bp = &whHiL[cb][fr*WHS + sh0];
        s16x4 b0 = *(const s16x4*)bp;
        s16x4 b1 = *(const s16x4*)(bp+4);
        s16x8 bhi = __builtin_shufflevector(b0,b1,0,1,2,3,4,5,6,7);
        if (aq == 0){
          acc0 = __builtin_amdgcn_mfma_f32_32x32x16_bf16(ahi, bhi, acc0, 0,0,0);
          acc0 = __builtin_amdgcn_mfma_f32_32x32x16_bf16(alo, bhi, acc0, 0,0,0);
        } else {
          acc1 = __builtin_amdgcn_mfma_f32_32x32x16_bf16(ahi, bhi, acc1, 0,0,0);
          acc1 = __builtin_amdgcn_mfma_f32_32x32x16_bf16(alo, bhi, acc1, 0,0,0);
        }
      }
      __builtin_amdgcn_s_setprio(0);
    }
    if (c<63) WRITE(cb ^ 1);   // other buffer; safe: all waves past barrier(c)
    mword = mword_nx;
  }

  // lsum partials
  lsum += __shfl_xor(lsum, 32);
  if (l < 32) lsP[ihalf][ks*2+fhalf][l] = lsum;

  // acc reduce across ks via t1L reuse (4 rounds of 8KB)
  float* redbuf = t1L;
  __syncthreads();
  #pragma unroll
  for (int ihr=0; ihr<2; ihr++){
    if (ks==1 && ihalf==ihr){
      #pragma unroll
      for (int e=0;e<16;e++) redbuf[(fhalf*64 + l)*16 + e] = acc0[e];
    }
    __syncthreads();
    if (ks==0 && ihalf==ihr){
      #pragma unroll
      for (int e=0;e<16;e++) acc0[e] += redbuf[(fhalf*64 + l)*16 + e];
    }
    __syncthreads();
    if (ks==1 && ihalf==ihr){
      #pragma unroll
      for (int e=0;e<16;e++) redbuf[(fhalf*64 + l)*16 + e] = acc1[e];
    }
    __syncthreads();
    if (ks==0 && ihalf==ihr){
      #pragma unroll
      for (int e=0;e<16;e++) acc1[e] += redbuf[(fhalf*64 + l)*16 + e];
    }
    __syncthreads();
  }

  if (t < 64){
    int ih2 = t >> 5, lr = t & 31;
    float s4 = lsP[ih2][0][lr] + lsP[ih2][1][lr] + lsP[ih2][2][lr] + lsP[ih2][3][lr];
    invL[t] = 1.0f / s4;
  }
  __syncthreads();

  if (ks == 0){
    float* hpb = hpWS + ((size_t)bh*N_ + n0 + ihalf*32)*F_ + fhalf*64 + ln;
    #pragma unroll
    for (int q4=0;q4<4;q4++){
      #pragma unroll
      for (int rr=0;rr<4;rr++){
        int r = q4*4+rr;
        int irl = rr + 8*q4 + 4*lg;
        float inv = invL[ihalf*32 + irl];
        float v0 = acc0[r]*inv;
        v0 = v0 > 0.f ? v0 : expm1f(v0);
        hpb[(size_t)irl*F_] = v0;
        float v1 = acc1[r]*inv;
        v1 = v1 > 0.f ? v1 : expm1f(v1);
        hpb[(size_t)irl*F_ + 32] = v1;
      }
    }
  }
}

// ---------------- Kernel 4: projection, head split across waves (layer 0) ----------------
__global__ void __launch_bounds__(256) proj_kernel(
    const float* __restrict__ hpWS,
    const float* __restrict__ pw_l,
    const float* __restrict__ pb_l,
    float* __restrict__ h_out)
{
  int v = blockIdx.x;          // 1024 blocks: b(4) x 256 tiles of 8 rows
  int b = v >> 8;
  int n0 = (v & 255) * 8;
  int t = threadIdx.x;
  int w = t >> 6, l = t & 63;
  int tcol = l & 31, rhalf = l >> 5;
  int c0 = tcol * 4;

  __shared__ float xsp[4][8][128];
  __shared__ float pacc[4][8][128];
  for (int idx = t; idx < 1024; idx += 256){
    int kh = idx >> 8, r = (idx >> 5) & 7, f4 = idx & 31;
    *(v4*)&xsp[kh][r][f4*4] =
      *(const v4*)(hpWS + ((size_t)(b*H_+kh)*N_ + n0 + r)*F_ + f4*4);
  }
  __syncthreads();

  v4 acc[4];
  #pragma unroll
  for (int r=0;r<4;r++) acc[r] = (v4)0.f;
  const float* pwk = pw_l + (size_t)w*128*F_;
  #pragma unroll 4
  for (int k=0;k<128;k++){
    v4 wv = *(const v4*)(pwk + (size_t)k*F_ + c0);
    #pragma unroll
    for (int r=0;r<4;r++) acc[r] += xsp[w][rhalf*4+r][k]*wv;
  }
  #pragma unroll
  for (int r=0;r<4;r++)
    *(v4*)&pacc[w][rhalf*4+r][c0] = acc[r];
  __syncthreads();

  int row = t >> 5, cb = (t & 31)*4;
  v4 s = *(const v4*)&pacc[0][row][cb];
  s += *(const v4*)&pacc[1][row][cb];
  s += *(const v4*)&pacc[2][row][cb];
  s += *(const v4*)&pacc[3][row][cb];
  s += *(const v4*)(pb_l + cb);
  *(v4*)(h_out + (size_t)(b*N_ + n0 + row)*F_ + cb) = s;
}

// ---------------- Kernel 4b: projection + output head fused (layer 1) ----------------
__global__ void __launch_bounds__(256) proj_out_kernel(
    const float* __restrict__ hpWS,
    const float* __restrict__ pw_l,
    const float* __restrict__ pb_l,
    const float* __restrict__ deltas,
    const float* __restrict__ alpha,
    const float* __restrict__ beta,
    const float* __restrict__ ow1, const float* __restrict__ ob1,
    const float* __restrict__ ow2, const float* __restrict__ ob2,
    float* __restrict__ out)
{
  int v = blockIdx.x;          // 1024 blocks: b(4) x 256 tiles of 8 rows
  int b = v >> 8;
  int n0 = (v & 255) * 8;
  int t = threadIdx.x;
  int w = t >> 6, l = t & 63;
  int tcol = l & 31, rhalf = l >> 5;
  int c0 = tcol * 4;

  __shared__ float xsp[4][8][128];
  __shared__ float pacc[4][8][128];
  for (int idx = t; idx < 1024; idx += 256){
    int kh = idx >> 8, r = (idx >> 5) & 7, f4 = idx & 31;
    *(v4*)&xsp[kh][r][f4*4] =
      *(const v4*)(hpWS + ((size_t)(b*H_+kh)*N_ + n0 + r)*F_ + f4*4);
  }
  __syncthreads();

  v4 acc[4];
  #pragma unroll
  for (int r=0;r<4;r++) acc[r] = (v4)0.f;
  const float* pwk = pw_l + (size_t)w*128*F_;
  #pragma unroll 4
  for (int k=0;k<128;k++){
    v4 wv = *(const v4*)(pwk + (size_t)k*F_ + c0);
    #pragma unroll
    for (int r=0;r<4;r++) acc[r] += xsp[w][rhalf*4+r][k]*wv;
  }
  #pragma unroll
  for (int r=0;r<4;r++)
    *(v4*)&pacc[w][rhalf*4+r][c0] = acc[r];
  __syncthreads();

  int row = t >> 5, cb = (t & 31)*4;
  {
    v4 s = *(const v4*)&pacc[0][row][cb];
    s += *(const v4*)&pacc[1][row][cb];
    s += *(const v4*)&pacc[2][row][cb];
    s += *(const v4*)&pacc[3][row][cb];
    s += *(const v4*)(pb_l + cb);
    *(v4*)&xsp[0][row][cb] = s;     // stage full h rows in LDS (xsp reads done)
  }
  __syncthreads();

  // output head: u = gelu(h@ow1+ob1); prop = u@ow2 + ob2; blend
  int il = t >> 5;                 // row 0..7
  int c2 = (t & 31) * 2;           // 2 of 64 ow1 cols
  float u0 = ob1[c2], u1 = ob1[c2+1];
  const float* hr = xsp[0][il];
  #pragma unroll 4
  for (int k=0;k<F_;k++){
    float hv = hr[k];
    v2 wv = *(const v2*)(ow1 + (size_t)k*64 + c2);
    u0 += hv*wv.x; u1 += hv*wv.y;
  }
  float pp = gelu_f(u0)*ow2[c2] + gelu_f(u1)*ow2[c2+1];
  pp += __shfl_xor(pp, 1);
  pp += __shfl_xor(pp, 2);
  pp += __shfl_xor(pp, 4);
  pp += __shfl_xor(pp, 8);
  pp += __shfl_xor(pp, 16);
  if ((t & 31) == 0){
    int n = n0 + il;
    size_t rowg = (size_t)b*N_ + n;
    float prop = pp + ob2[0];
    out[rowg] = sigmoid_f(alpha[n]) * deltas[rowg] + beta[0]*prop;
  }
}

extern "C" void kernel_launch(void* const* d_in, const int* in_sizes, int n_in,
                              void* d_out, int out_size, void* d_ws, size_t ws_size,
                              hipStream_t stream) {
  const float* deltas = (const float*)d_in[0];
  const float* evt    = (const float*)d_in[1];
  const float* adj    = (const float*)d_in[2];
  const float* mw1 = (const float*)d_in[3];
  const float* mb1 = (const float*)d_in[4];
  const float* mw2 = (const float*)d_in[5];
  const float* mb2 = (const float*)d_in[6];
  const float* mw3 = (const float*)d_in[7];
  const float* mb3 = (const float*)d_in[8];
  const float* gw1 = (const float*)d_in[9];
  const float* gb1 = (const float*)d_in[10];
  const float* gw2 = (const float*)d_in[11];
  const float* gb2 = (const float*)d_in[12];
  const float* Wg  = (const float*)d_in[13];
  const float* a_src = (const float*)d_in[14];
  const float* a_dst = (const float*)d_in[15];
  const float* pw = (const float*)d_in[16];
  const float* pb = (const float*)d_in[17];
  const float* ow1 = (const float*)d_in[18];
  const float* ob1 = (const float*)d_in[19];
  const float* ow2 = (const float*)d_in[20];
  const float* ob2 = (const float*)d_in[21];
  const float* alpha = (const float*)d_in[22];
  const float* beta  = (const float*)d_in[23];
  float* out = (float*)d_out;

  float* ws = (float*)d_ws;
  float* hA = ws;
  float* hB = hA + (size_t)B_*N_*F_;
  short* WhT_hi = (short*)(hB + (size_t)B_*N_*F_);
  short* WhT_lo = WhT_hi + (size_t)B_*H_*F_*N_;   // region kept reserved (unused)
  float* hp = (float*)(WhT_lo + (size_t)B_*H_*F_*N_);
  float* sA = hp + (size_t)B_*H_*N_*F_;           // [2][16][N] partials
  float* tA = sA + (size_t)2*B_*H_*N_;            // [2][16][N] partials
  unsigned* maskT = (unsigned*)(tA + (size_t)2*B_*H_*N_);
  float* w1m = (float*)(maskT + (size_t)B_*64*N_);
  float* s1ws = hp;   // dead until first attn

  int BN = B_*N_;
  w1m_kernel<<<385, 192, 0, stream>>>(mw1, gw1, w1m);
  mask_kernel<<<B_*64, 256, 0, stream>>>(adj, maskT);
  mlp1_kernel<<<BN/8, 256, 0, stream>>>(deltas, evt, w1m, mb1, gb1, s1ws);
  mlp2_kernel<<<BN/8, 256, 0, stream>>>(s1ws, mw2, mb2, mw3, mb3, gw2, gb2, hA);

  // layer 0
  wh_kernel<<<16*2*32, 256, 0, stream>>>(hA,
      Wg, a_src, a_dst, WhT_hi, sA, tA);
  attn_kernel<<<512, 512, 0, stream>>>(maskT, WhT_hi, sA, tA, hp);
  proj_kernel<<<1024, 256, 0, stream>>>(hp, pw, pb, hB);

  // layer 1 (projection fused with output head)
  wh_kernel<<<16*2*32, 256, 0, stream>>>(hB,
      Wg + (size_t)H_*F_*F_, a_src + (size_t)H_*F_, a_dst + (size_t)H_*F_,
      WhT_hi, sA, tA);
  attn_kernel<<<512, 512, 0, stream>>>(maskT, WhT_hi, sA, tA, hp);
  proj_out_kernel<<<1024, 256, 0, stream>>>(hp,
      pw + (size_t)H_*F_*F_, pb + (size_t)F_,
      deltas, alpha, beta, ow1, ob1, ow2, ob2, out);
}

// Round 14
// 293.300 us; speedup vs baseline: 1.0264x; 1.0264x over previous
//
#include <hip/hip_runtime.h>
#include <hip/hip_bf16.h>
#include <math.h>

#define B_ 4
#define N_ 2048
#define F_ 128
#define H_ 4
#define NEG_BIG_F -9.0e15f
#define L2E 1.44269504088896f

typedef float v2 __attribute__((ext_vector_type(2)));
typedef float v4 __attribute__((ext_vector_type(4)));
typedef float f32x16 __attribute__((ext_vector_type(16)));
typedef short s16x8 __attribute__((ext_vector_type(8)));
typedef short s16x4 __attribute__((ext_vector_type(4)));
typedef unsigned u32x4 __attribute__((ext_vector_type(4)));
typedef unsigned u32x2 __attribute__((ext_vector_type(2)));

__device__ __forceinline__ float gelu_f(float x){
  return 0.5f*x*(1.0f+erff(x*0.70710678118654752f));
}
__device__ __forceinline__ float sigmoid_f(float x){
  return 1.0f/(1.0f+__expf(-x));
}
__device__ __forceinline__ short bfbits(float v){
  __hip_bfloat16 h = __float2bfloat16(v);
  short r; __builtin_memcpy(&r, &h, 2); return r;
}
// pack hi16(a), hi16(b) -> u32 (low short = hi16(a))
__device__ __forceinline__ unsigned packhi(float a, float b){
  return __builtin_amdgcn_perm(__float_as_uint(b), __float_as_uint(a), 0x07060302u);
}
__device__ __forceinline__ unsigned cvtpk_bf16(float a, float b){
  unsigned r;
  asm("v_cvt_pk_bf16_f32 %0, %1, %2" : "=v"(r) : "v"(a), "v"(b));
  return r;
}
__device__ __forceinline__ float exp2_f(float x){
  float r;
  asm("v_exp_f32 %0, %1" : "=v"(r) : "v"(x));
  return r;
}

// ---------------- Kernel 0: adjacency -> transposed bitmask maskT[b][word][n] ----------------
__global__ void __launch_bounds__(256) mask_kernel(
    const float* __restrict__ adj, unsigned* __restrict__ maskT)
{
  int v = blockIdx.x;            // b(4) x 64 tiles of 32 rows
  int b = v >> 6; int n0 = (v & 63) * 32;
  int t = threadIdx.x;
  int r = t >> 3, jg = t & 7;
  __shared__ unsigned mw[32][65];
  const float* arow = adj + (size_t)(b*N_ + n0 + r)*N_;
  for (int wq=0; wq<8; wq++){
    int wdi = jg + 8*wq;
    unsigned bits = 0;
    #pragma unroll
    for (int m=0;m<8;m++){
      v4 a = *(const v4*)(arow + wdi*32 + m*4);
      bits |= (a.x>0.f?1u:0u)<<(m*4);
      bits |= (a.y>0.f?1u:0u)<<(m*4+1);
      bits |= (a.z>0.f?1u:0u)<<(m*4+2);
      bits |= (a.w>0.f?1u:0u)<<(m*4+3);
    }
    mw[r][wdi] = bits;
  }
  __syncthreads();
  #pragma unroll
  for (int q=0;q<8;q++){
    int idx = t + q*256;
    int wdi = idx >> 5, rr = idx & 31;
    maskT[((size_t)b*64 + wdi)*N_ + n0 + rr] = mw[rr][wdi];
  }
}

// ---------------- Kernel 0b: merge mw1||gw1 into w1m[385][192] ----------------
__global__ void __launch_bounds__(192) w1m_kernel(
    const float* __restrict__ mw1, const float* __restrict__ gw1,
    float* __restrict__ w1m)
{
  int k = blockIdx.x;      // 0..384
  int c = threadIdx.x;     // 0..191
  w1m[(size_t)k*192 + c] = (c < 128) ? mw1[(size_t)k*128 + c]
                                     : gw1[(size_t)k*64 + (c-128)];
}

// ---------------- Kernel 1a: stage-1 MLP, K split across waves ----------------
__global__ void __launch_bounds__(256) mlp1_kernel(
    const float* __restrict__ deltas, const float* __restrict__ evt,
    const float* __restrict__ w1m,
    const float* __restrict__ mb1, const float* __restrict__ gb1,
    float* __restrict__ s1ws)
{
  int row0 = blockIdx.x * 8;       // 1024 blocks
  int t = threadIdx.x;
  int w = t >> 6, l = t & 63;
  int tcol = l & 31, rhalf = l >> 5;
  int c0 = tcol * 6;
  __shared__ float xs[8][392];
  __shared__ float pacc[4][8][192];

  for (int idx = t; idx < 8*385; idx += 256){
    int i = idx / 385;
    int k = idx - i*385;
    xs[i][k] = (k==0) ? deltas[row0+i] : evt[(size_t)(row0+i)*384 + (k-1)];
  }
  __syncthreads();

  int kstart = (w*385) >> 2, kend = ((w+1)*385) >> 2;
  float acc[4][6];
  #pragma unroll
  for (int r=0;r<4;r++)
    #pragma unroll
    for (int e=0;e<6;e++) acc[r][e] = 0.f;

  #pragma unroll 4
  for (int k=kstart; k<kend; k++){
    const float* wp = w1m + (size_t)k*192 + c0;
    v2 wa = *(const v2*)wp;
    v2 wb = *(const v2*)(wp+2);
    v2 wc = *(const v2*)(wp+4);
    #pragma unroll
    for (int r=0;r<4;r++){
      float x = xs[rhalf*4+r][k];
      acc[r][0] += x*wa.x; acc[r][1] += x*wa.y;
      acc[r][2] += x*wb.x; acc[r][3] += x*wb.y;
      acc[r][4] += x*wc.x; acc[r][5] += x*wc.y;
    }
  }
  #pragma unroll
  for (int r=0;r<4;r++){
    float* pp = &pacc[w][rhalf*4+r][c0];
    #pragma unroll
    for (int e=0;e<6;e++) pp[e] = acc[r][e];
  }
  __syncthreads();

  int row = t >> 5, cc0 = (t & 31) * 6;
  #pragma unroll
  for (int e=0;e<6;e++){
    int c = cc0 + e;
    float s = pacc[0][row][c] + pacc[1][row][c] + pacc[2][row][c] + pacc[3][row][c];
    s += (c < 128) ? mb1[c] : gb1[c-128];
    s1ws[(size_t)(row0+row)*192 + c] = gelu_f(s);
  }
}

// ---------------- Kernel 1b: stages 2+3, K split across waves ----------------
__global__ void __launch_bounds__(256) mlp2_kernel(
    const float* __restrict__ s1ws,
    const float* __restrict__ mw2, const float* __restrict__ mb2,
    const float* __restrict__ mw3, const float* __restrict__ mb3,
    const float* __restrict__ gw2, const float* __restrict__ gb2,
    float* __restrict__ h_out)
{
  int row0 = blockIdx.x * 8;       // 1024 blocks
  int t = threadIdx.x;
  int w = t >> 6, l = t & 63;
  int tcol = l & 31, rhalf = l >> 5;
  int c0 = tcol * 4;

  __shared__ float sm[1600 + 2048 + 2048 + 1024];
  float (*xs)[200] = (float(*)[200])sm;
  float* mpart = sm + 1600;       // [2][8][128]
  float* gpart = sm + 1600 + 2048;// [2][8][128]
  float* xs2   = sm + 1600 + 4096;// [8][128]
  float* p3    = sm + 1600;       // reuse mpart+gpart: [4][8][128]

  for (int idx = t; idx < 8*48; idx += 256){
    int i = idx / 48, c4 = idx - i*48;
    *(v4*)&xs[i][c4*4] = *(const v4*)(s1ws + (size_t)(row0+i)*192 + c4*4);
  }
  __syncthreads();

  // stage A
  {
    v4 acc[4];
    #pragma unroll
    for (int r=0;r<4;r++) acc[r] = (v4)0.f;
    if (w < 2){
      int ks2 = w*64;
      #pragma unroll 4
      for (int k=ks2; k<ks2+64; k++){
        v4 wv = *(const v4*)(mw2 + (size_t)k*128 + c0);
        #pragma unroll
        for (int r=0;r<4;r++) acc[r] += xs[rhalf*4+r][k]*wv;
      }
      #pragma unroll
      for (int r=0;r<4;r++)
        *(v4*)&mpart[((size_t)w*8 + rhalf*4+r)*128 + c0] = acc[r];
    } else {
      int ks2 = (w-2)*32;
      #pragma unroll 4
      for (int k=ks2; k<ks2+32; k++){
        v4 wv = *(const v4*)(gw2 + (size_t)k*128 + c0);
        #pragma unroll
        for (int r=0;r<4;r++) acc[r] += xs[rhalf*4+r][128+k]*wv;
      }
      #pragma unroll
      for (int r=0;r<4;r++)
        *(v4*)&gpart[((size_t)(w-2)*8 + rhalf*4+r)*128 + c0] = acc[r];
    }
  }
  __syncthreads();

  // stage B
  int row = t >> 5, cb = (t & 31) * 4;
  v4 gp;
  {
    v4 m2 = *(const v4*)&mpart[(size_t)row*128 + cb];
    m2 += *(const v4*)&mpart[(size_t)(8+row)*128 + cb];
    m2 += *(const v4*)(mb2 + cb);
    gp = *(const v4*)&gpart[(size_t)row*128 + cb];
    gp += *(const v4*)&gpart[(size_t)(8+row)*128 + cb];
    gp += *(const v4*)(gb2 + cb);
    v4 o;
    o.x = gelu_f(m2.x); o.y = gelu_f(m2.y); o.z = gelu_f(m2.z); o.w = gelu_f(m2.w);
    __syncthreads();               // mpart/gpart reads done before p3 overwrites
    *(v4*)&xs2[(size_t)row*128 + cb] = o;
  }
  __syncthreads();

  // stage C
  {
    v4 acc3[4];
    #pragma unroll
    for (int r=0;r<4;r++) acc3[r] = (v4)0.f;
    int kc = w*32;
    #pragma unroll 4
    for (int k=kc; k<kc+32; k++){
      v4 wv = *(const v4*)(mw3 + (size_t)k*128 + c0);
      #pragma unroll
      for (int r=0;r<4;r++) acc3[r] += xs2[(size_t)(rhalf*4+r)*128 + k]*wv;
    }
    #pragma unroll
    for (int r=0;r<4;r++)
      *(v4*)&p3[((size_t)w*8 + rhalf*4+r)*128 + c0] = acc3[r];
  }
  __syncthreads();

  {
    v4 s = *(const v4*)&p3[(size_t)row*128 + cb];
    s += *(const v4*)&p3[(size_t)(8+row)*128 + cb];
    s += *(const v4*)&p3[(size_t)(16+row)*128 + cb];
    s += *(const v4*)&p3[(size_t)(24+row)*128 + cb];
    s += *(const v4*)(mb3 + cb);
    v4 o;
    o.x = s.x * sigmoid_f(gp.x);
    o.y = s.y * sigmoid_f(gp.y);
    o.z = s.z * sigmoid_f(gp.z);
    o.w = s.w * sigmoid_f(gp.w);
    *(v4*)(h_out + (size_t)(row0+row)*F_ + cb) = o;
  }
}

// ---------------- Kernel 2: WhT (bf16 RNE, [bh][f][n]) + s,t dots; 64 rows/block (R9 version) ----------------
__global__ void __launch_bounds__(256) wh_kernel(
    const float* __restrict__ h,
    const float* __restrict__ Wg_l,
    const float* __restrict__ asrc_l,
    const float* __restrict__ adst_l,
    short* __restrict__ WhT_hi,
    float* __restrict__ sArr,
    float* __restrict__ tArr)
{
  int v = blockIdx.x;
  int itile = v & 31;
  int bh = v >> 5;
  int b = bh >> 2, hh = bh & 3;
  int n0 = itile * 64;
  int t = threadIdx.x;
  int i0  = (t & 7) * 8;
  int fo0 = (t >> 3) * 4;

  __shared__ float hT[128][72];
  __shared__ float sP[4][64], tP[4][64];
  for (int idx = t; idx < 64*128; idx += 256){
    int i = idx >> 7, k = idx & 127;
    hT[k][i] = h[(size_t)(b*N_ + n0 + i)*F_ + k];
  }
  __syncthreads();

  const float* W = Wg_l + (size_t)hh*F_*F_;
  v4 accA[4], accB[4];
  #pragma unroll
  for (int c=0;c<4;c++){ accA[c]=(v4)0.f; accB[c]=(v4)0.f; }
  #pragma unroll 4
  for (int k=0;k<F_;k++){
    v4 w = *(const v4*)(W + (size_t)k*F_ + fo0);
    v4 ha = *(const v4*)&hT[k][i0];
    v4 hb = *(const v4*)&hT[k][i0+4];
    accA[0]+=w.x*ha; accA[1]+=w.y*ha; accA[2]+=w.z*ha; accA[3]+=w.w*ha;
    accB[0]+=w.x*hb; accB[1]+=w.y*hb; accB[2]+=w.z*hb; accB[3]+=w.w*hb;
  }
  #pragma unroll
  for (int c=0;c<4;c++){
    s16x8 hi8;
    #pragma unroll
    for (int e=0;e<8;e++){
      float x = (e<4) ? accA[c][e] : accB[c][e-4];
      hi8[e] = bfbits(x);           // RNE bf16
    }
    size_t off = ((size_t)bh*F_ + fo0 + c)*N_ + n0 + i0;
    *(s16x8*)(WhT_hi + off) = hi8;
  }
  v4 as4 = *(const v4*)(asrc_l + hh*F_ + fo0);
  v4 ad4 = *(const v4*)(adst_l + hh*F_ + fo0);
  v4 sva = accA[0]*as4.x + accA[1]*as4.y + accA[2]*as4.z + accA[3]*as4.w;
  v4 svb = accB[0]*as4.x + accB[1]*as4.y + accB[2]*as4.z + accB[3]*as4.w;
  v4 tva = accA[0]*ad4.x + accA[1]*ad4.y + accA[2]*ad4.z + accA[3]*ad4.w;
  v4 tvb = accB[0]*ad4.x + accB[1]*ad4.y + accB[2]*ad4.z + accB[3]*ad4.w;
  #pragma unroll
  for (int m=8;m<=32;m<<=1){
    sva.x+=__shfl_xor(sva.x,m); sva.y+=__shfl_xor(sva.y,m); sva.z+=__shfl_xor(sva.z,m); sva.w+=__shfl_xor(sva.w,m);
    svb.x+=__shfl_xor(svb.x,m); svb.y+=__shfl_xor(svb.y,m); svb.z+=__shfl_xor(svb.z,m); svb.w+=__shfl_xor(svb.w,m);
    tva.x+=__shfl_xor(tva.x,m); tva.y+=__shfl_xor(tva.y,m); tva.z+=__shfl_xor(tva.z,m); tva.w+=__shfl_xor(tva.w,m);
    tvb.x+=__shfl_xor(tvb.x,m); tvb.y+=__shfl_xor(tvb.y,m); tvb.z+=__shfl_xor(tvb.z,m); tvb.w+=__shfl_xor(tvb.w,m);
  }
  int wv = t >> 6;
  if ((t & 56) == 0){
    *(v4*)&sP[wv][i0] = sva; *(v4*)&sP[wv][i0+4] = svb;
    *(v4*)&tP[wv][i0] = tva; *(v4*)&tP[wv][i0+4] = tvb;
  }
  __syncthreads();
  if (t < 64){
    sArr[(size_t)bh*N_ + n0 + t] = sP[0][t]+sP[1][t]+sP[2][t]+sP[3][t];
    tArr[(size_t)bh*N_ + n0 + t] = tP[0][t]+tP[1][t]+tP[2][t]+tP[3][t];
  }
}

// ---------------- Kernel 3: MFMA masked-softmax + PV (P hi/lo split, Wh bf16-RNE) ----------------
#define WHS 44   // whT LDS stride in shorts (88B rows)
#define PBS 18   // pbuf row stride in u32 (72B rows: 2-way banks)
__global__ void __launch_bounds__(512) attn_kernel(
    const unsigned* __restrict__ maskT,
    const short* __restrict__ WhT_hi,
    const float* __restrict__ sArr,
    const float* __restrict__ tArr,
    float* __restrict__ hpWS)
{
  int v = blockIdx.x;           // 512 blocks, XCD swizzle
  int seq = v >> 3, x8 = v & 7;
  int bh = (seq >> 5)*8 + x8;
  int itile = seq & 31;
  int b = bh >> 2;
  int n0 = itile * 64;
  int t = threadIdx.x;
  int w = t >> 6, l = t & 63;
  int lg = l >> 5, ln = l & 31;
  int ihalf = w & 1;
  int ks    = (w >> 1) & 1;
  int fhalf = w >> 2;

  __shared__ float t1L[N_];            // t * log2e (t2 = 0.2*t1 via fmaf); reused as acc-reduce buffer
  __shared__ short whHiL[2][128*WHS];
  __shared__ unsigned pbufHi[2][2][32][PBS];
  __shared__ unsigned pbufLo[2][2][32][PBS];
  __shared__ float mxPart[8][64];
  __shared__ float mxL[64], amArgL[64], invL[64];
  __shared__ float lsP[2][4][32];

  const float* tp = tArr + (size_t)bh*N_;
  #pragma unroll
  for (int q=0;q<4;q++){
    t1L[t + q*512] = tp[t + q*512] * L2E;
  }

  // staging: 512 threads, 1 hi s16x8 each per tile
  s16x8 rh;
  int srow = t >> 2, sseg = t & 3;
  const short* gHi = WhT_hi + (size_t)bh*F_*N_;
  auto STAGE = [&](int jj0){
    size_t o = (size_t)srow*N_ + jj0 + sseg*8;
    rh = *(const s16x8*)(gHi + o);
  };
  auto WRITE = [&](int buf){
    int wo = srow*WHS + sseg*8;
    *(s16x4*)&whHiL[buf][wo]   = __builtin_shufflevector(rh,rh,0,1,2,3);
    *(s16x4*)&whHiL[buf][wo+4] = __builtin_shufflevector(rh,rh,4,5,6,7);
  };

  STAGE(0);
  int il = t & 63, qq = t >> 6;
  float s_il = sArr[(size_t)bh*N_ + n0 + il];
  float s1_il = s_il * L2E, s2_il = s_il * (0.2f*L2E);
  __syncthreads();   // t1L ready

  // phase 1: per-row max over active j, in exp2-scaled space (t2 = 0.2*t1)
  float mx = NEG_BIG_F;
  const unsigned* mb1p = maskT + (size_t)b*64*N_ + n0;
  for (int wq=0; wq<8; wq++){
    int wdi = qq + wq*8;
    unsigned wd = mb1p[(size_t)wdi*N_ + il];
    while (wd){
      int k2 = __builtin_ctz(wd); wd &= wd - 1;
      float t1v = t1L[wdi*32 + k2];
      float e = fmaxf(s1_il + t1v, fmaf(0.2f, t1v, s2_il));
      mx = fmaxf(mx, e);
    }
  }
  mxPart[qq][il] = mx;
  WRITE(0);
  __syncthreads();
  if (t < 64){
    float m = mxPart[0][t];
    #pragma unroll
    for (int q=1;q<8;q++) m = fmaxf(m, mxPart[q][t]);
    bool am = (m <= -8.0e15f);
    mxL[t] = am ? 0.f : m;
    amArgL[t] = am ? 0.f : -1.0e30f;
  }
  __syncthreads();

  // lane constants (exp2-space, mx folded in)
  int irow = n0 + ihalf*32 + ln;
  float s_lane  = sArr[(size_t)bh*N_ + irow];
  float mx_lane = mxL[ihalf*32 + ln];
  float amArg_lane = amArgL[ihalf*32 + ln];
  float Ac = s_lane*L2E - mx_lane;
  float Bc = s_lane*(0.2f*L2E) - mx_lane;
  const unsigned* mrow = maskT + (size_t)b*64*N_ + irow;

  f32x16 acc0, acc1;
  #pragma unroll
  for (int e2=0;e2<16;e2++){ acc0[e2]=0.f; acc1[e2]=0.f; }
  float lsum = 0.f;

  int jsub = ks*16 + fhalf*8 + lg*4;   // this lane's 4 p's
  int qidx = jsub >> 1;                 // u32 pair index (even)
  int sh0 = ks*16 + lg*8;               // this wave's A/B k-slot base

  unsigned mword = mrow[0];
  for (int c=0;c<64;c++){
    int j0 = c*32;
    int cb = c & 1;
    unsigned mword_nx = (c<63) ? mrow[(size_t)(c+1)*N_] : 0u;
    if (c<63) STAGE(j0 + 32);

    // ---- p-build: 4 values; arg = max(Ac+t1, fmaf(0.2,t1,Bc)); pe = exp2(sel) ----
    {
      v4 ta1 = *(const v4*)&t1L[j0 + jsub];
      unsigned mm = mword >> jsub;
      float a0 = fmaxf(Ac + ta1.x, fmaf(0.2f, ta1.x, Bc));
      float a1 = fmaxf(Ac + ta1.y, fmaf(0.2f, ta1.y, Bc));
      float a2 = fmaxf(Ac + ta1.z, fmaf(0.2f, ta1.z, Bc));
      float a3 = fmaxf(Ac + ta1.w, fmaf(0.2f, ta1.w, Bc));
      float pe0 = exp2_f((mm & 1u)      ? a0 : amArg_lane);
      float pe1 = exp2_f(((mm>>1) & 1u) ? a1 : amArg_lane);
      float pe2 = exp2_f(((mm>>2) & 1u) ? a2 : amArg_lane);
      float pe3 = exp2_f(((mm>>3) & 1u) ? a3 : amArg_lane);
      lsum += (pe0+pe1)+(pe2+pe3);
      u32x2 hiP, loP;
      hiP[0] = packhi(pe0, pe1);
      hiP[1] = packhi(pe2, pe3);
      float l0 = pe0 - __uint_as_float(__float_as_uint(pe0)&0xffff0000u);
      float l1 = pe1 - __uint_as_float(__float_as_uint(pe1)&0xffff0000u);
      float l2 = pe2 - __uint_as_float(__float_as_uint(pe2)&0xffff0000u);
      float l3 = pe3 - __uint_as_float(__float_as_uint(pe3)&0xffff0000u);
      loP[0] = cvtpk_bf16(l0, l1);
      loP[1] = cvtpk_bf16(l2, l3);
      *(u32x2*)&pbufHi[cb][ihalf][ln][qidx] = hiP;
      *(u32x2*)&pbufLo[cb][ihalf][ln][qidx] = loP;
    }
    __syncthreads();   // pbuf(c) + whL(c) ready; prev-iter reads all done

    // ---- MFMA: acc = (Phi + Plo) · Whhi ; 2 f-quadrant accs x 2 terms ----
    {
      int aq0 = ks*8 + lg*4;
      u32x2 ha2 = *(const u32x2*)&pbufHi[cb][ihalf][ln][aq0];
      u32x2 hb2 = *(const u32x2*)&pbufHi[cb][ihalf][ln][aq0+2];
      u32x2 la2 = *(const u32x2*)&pbufLo[cb][ihalf][ln][aq0];
      u32x2 lb2 = *(const u32x2*)&pbufLo[cb][ihalf][ln][aq0+2];
      u32x4 h4; h4[0]=ha2[0]; h4[1]=ha2[1]; h4[2]=hb2[0]; h4[3]=hb2[1];
      u32x4 l4; l4[0]=la2[0]; l4[1]=la2[1]; l4[2]=lb2[0]; l4[3]=lb2[1];
      s16x8 ahi = __builtin_bit_cast(s16x8, h4);
      s16x8 alo = __builtin_bit_cast(s16x8, l4);
      __builtin_amdgcn_s_setprio(1);
      #pragma unroll
      for (int aq=0; aq<2; aq++){
        int fr = fhalf*64 + aq*32 + ln;
        const short* bp = &whHiL[cb][fr*WHS + sh0];
        s16x4 b0 = *(const s16x4*)bp;
        s16x4 b1 = *(const s16x4*)(bp+4);
        s16x8 bhi = __builtin_shufflevector(b0,b1,0,1,2,3,4,5,6,7);
        if (aq == 0){
          acc0 = __builtin_amdgcn_mfma_f32_32x32x16_bf16(ahi, bhi, acc0, 0,0,0);
          acc0 = __builtin_amdgcn_mfma_f32_32x32x16_bf16(alo, bhi, acc0, 0,0,0);
        } else {
          acc1 = __builtin_amdgcn_mfma_f32_32x32x16_bf16(ahi, bhi, acc1, 0,0,0);
          acc1 = __builtin_amdgcn_mfma_f32_32x32x16_bf16(alo, bhi, acc1, 0,0,0);
        }
      }
      __builtin_amdgcn_s_setprio(0);
    }
    if (c<63) WRITE(cb ^ 1);   // other buffer; safe: all waves past barrier(c)
    mword = mword_nx;
  }

  // lsum partials
  lsum += __shfl_xor(lsum, 32);
  if (l < 32) lsP[ihalf][ks*2+fhalf][l] = lsum;

  // acc reduce across ks via t1L reuse (4 rounds of 8KB)
  float* redbuf = t1L;
  __syncthreads();
  #pragma unroll
  for (int ihr=0; ihr<2; ihr++){
    if (ks==1 && ihalf==ihr){
      #pragma unroll
      for (int e=0;e<16;e++) redbuf[(fhalf*64 + l)*16 + e] = acc0[e];
    }
    __syncthreads();
    if (ks==0 && ihalf==ihr){
      #pragma unroll
      for (int e=0;e<16;e++) acc0[e] += redbuf[(fhalf*64 + l)*16 + e];
    }
    __syncthreads();
    if (ks==1 && ihalf==ihr){
      #pragma unroll
      for (int e=0;e<16;e++) redbuf[(fhalf*64 + l)*16 + e] = acc1[e];
    }
    __syncthreads();
    if (ks==0 && ihalf==ihr){
      #pragma unroll
      for (int e=0;e<16;e++) acc1[e] += redbuf[(fhalf*64 + l)*16 + e];
    }
    __syncthreads();
  }

  if (t < 64){
    int ih2 = t >> 5, lr = t & 31;
    float s4 = lsP[ih2][0][lr] + lsP[ih2][1][lr] + lsP[ih2][2][lr] + lsP[ih2][3][lr];
    invL[t] = 1.0f / s4;
  }
  __syncthreads();

  if (ks == 0){
    float* hpb = hpWS + ((size_t)bh*N_ + n0 + ihalf*32)*F_ + fhalf*64 + ln;
    #pragma unroll
    for (int q4=0;q4<4;q4++){
      #pragma unroll
      for (int rr=0;rr<4;rr++){
        int r = q4*4+rr;
        int irl = rr + 8*q4 + 4*lg;
        float inv = invL[ihalf*32 + irl];
        float v0 = acc0[r]*inv;
        v0 = v0 > 0.f ? v0 : expm1f(v0);
        hpb[(size_t)irl*F_] = v0;
        float v1 = acc1[r]*inv;
        v1 = v1 > 0.f ? v1 : expm1f(v1);
        hpb[(size_t)irl*F_ + 32] = v1;
      }
    }
  }
}

// ---------------- Kernel 4: projection, head split across waves (layer 0) ----------------
__global__ void __launch_bounds__(256) proj_kernel(
    const float* __restrict__ hpWS,
    const float* __restrict__ pw_l,
    const float* __restrict__ pb_l,
    float* __restrict__ h_out)
{
  int v = blockIdx.x;          // 1024 blocks: b(4) x 256 tiles of 8 rows
  int b = v >> 8;
  int n0 = (v & 255) * 8;
  int t = threadIdx.x;
  int w = t >> 6, l = t & 63;
  int tcol = l & 31, rhalf = l >> 5;
  int c0 = tcol * 4;

  __shared__ float xsp[4][8][128];
  __shared__ float pacc[4][8][128];
  for (int idx = t; idx < 1024; idx += 256){
    int kh = idx >> 8, r = (idx >> 5) & 7, f4 = idx & 31;
    *(v4*)&xsp[kh][r][f4*4] =
      *(const v4*)(hpWS + ((size_t)(b*H_+kh)*N_ + n0 + r)*F_ + f4*4);
  }
  __syncthreads();

  v4 acc[4];
  #pragma unroll
  for (int r=0;r<4;r++) acc[r] = (v4)0.f;
  const float* pwk = pw_l + (size_t)w*128*F_;
  #pragma unroll 4
  for (int k=0;k<128;k++){
    v4 wv = *(const v4*)(pwk + (size_t)k*F_ + c0);
    #pragma unroll
    for (int r=0;r<4;r++) acc[r] += xsp[w][rhalf*4+r][k]*wv;
  }
  #pragma unroll
  for (int r=0;r<4;r++)
    *(v4*)&pacc[w][rhalf*4+r][c0] = acc[r];
  __syncthreads();

  int row = t >> 5, cb = (t & 31)*4;
  v4 s = *(const v4*)&pacc[0][row][cb];
  s += *(const v4*)&pacc[1][row][cb];
  s += *(const v4*)&pacc[2][row][cb];
  s += *(const v4*)&pacc[3][row][cb];
  s += *(const v4*)(pb_l + cb);
  *(v4*)(h_out + (size_t)(b*N_ + n0 + row)*F_ + cb) = s;
}

// ---------------- Kernel 4b: projection + output head fused (layer 1) ----------------
__global__ void __launch_bounds__(256) proj_out_kernel(
    const float* __restrict__ hpWS,
    const float* __restrict__ pw_l,
    const float* __restrict__ pb_l,
    const float* __restrict__ deltas,
    const float* __restrict__ alpha,
    const float* __restrict__ beta,
    const float* __restrict__ ow1, const float* __restrict__ ob1,
    const float* __restrict__ ow2, const float* __restrict__ ob2,
    float* __restrict__ out)
{
  int v = blockIdx.x;          // 1024 blocks: b(4) x 256 tiles of 8 rows
  int b = v >> 8;
  int n0 = (v & 255) * 8;
  int t = threadIdx.x;
  int w = t >> 6, l = t & 63;
  int tcol = l & 31, rhalf = l >> 5;
  int c0 = tcol * 4;

  __shared__ float xsp[4][8][128];
  __shared__ float pacc[4][8][128];
  for (int idx = t; idx < 1024; idx += 256){
    int kh = idx >> 8, r = (idx >> 5) & 7, f4 = idx & 31;
    *(v4*)&xsp[kh][r][f4*4] =
      *(const v4*)(hpWS + ((size_t)(b*H_+kh)*N_ + n0 + r)*F_ + f4*4);
  }
  __syncthreads();

  v4 acc[4];
  #pragma unroll
  for (int r=0;r<4;r++) acc[r] = (v4)0.f;
  const float* pwk = pw_l + (size_t)w*128*F_;
  #pragma unroll 4
  for (int k=0;k<128;k++){
    v4 wv = *(const v4*)(pwk + (size_t)k*F_ + c0);
    #pragma unroll
    for (int r=0;r<4;r++) acc[r] += xsp[w][rhalf*4+r][k]*wv;
  }
  #pragma unroll
  for (int r=0;r<4;r++)
    *(v4*)&pacc[w][rhalf*4+r][c0] = acc[r];
  __syncthreads();

  int row = t >> 5, cb = (t & 31)*4;
  {
    v4 s = *(const v4*)&pacc[0][row][cb];
    s += *(const v4*)&pacc[1][row][cb];
    s += *(const v4*)&pacc[2][row][cb];
    s += *(const v4*)&pacc[3][row][cb];
    s += *(const v4*)(pb_l + cb);
    *(v4*)&xsp[0][row][cb] = s;     // stage full h rows in LDS (xsp reads done)
  }
  __syncthreads();

  // output head: u = gelu(h@ow1+ob1); prop = u@ow2 + ob2; blend
  int il = t >> 5;                 // row 0..7
  int c2 = (t & 31) * 2;           // 2 of 64 ow1 cols
  float u0 = ob1[c2], u1 = ob1[c2+1];
  const float* hr = xsp[0][il];
  #pragma unroll 4
  for (int k=0;k<F_;k++){
    float hv = hr[k];
    v2 wv = *(const v2*)(ow1 + (size_t)k*64 + c2);
    u0 += hv*wv.x; u1 += hv*wv.y;
  }
  float pp = gelu_f(u0)*ow2[c2] + gelu_f(u1)*ow2[c2+1];
  pp += __shfl_xor(pp, 1);
  pp += __shfl_xor(pp, 2);
  pp += __shfl_xor(pp, 4);
  pp += __shfl_xor(pp, 8);
  pp += __shfl_xor(pp, 16);
  if ((t & 31) == 0){
    int n = n0 + il;
    size_t rowg = (size_t)b*N_ + n;
    float prop = pp + ob2[0];
    out[rowg] = sigmoid_f(alpha[n]) * deltas[rowg] + beta[0]*prop;
  }
}

extern "C" void kernel_launch(void* const* d_in, const int* in_sizes, int n_in,
                              void* d_out, int out_size, void* d_ws, size_t ws_size,
                              hipStream_t stream) {
  const float* deltas = (const float*)d_in[0];
  const float* evt    = (const float*)d_in[1];
  const float* adj    = (const float*)d_in[2];
  const float* mw1 = (const float*)d_in[3];
  const float* mb1 = (const float*)d_in[4];
  const float* mw2 = (const float*)d_in[5];
  const float* mb2 = (const float*)d_in[6];
  const float* mw3 = (const float*)d_in[7];
  const float* mb3 = (const float*)d_in[8];
  const float* gw1 = (const float*)d_in[9];
  const float* gb1 = (const float*)d_in[10];
  const float* gw2 = (const float*)d_in[11];
  const float* gb2 = (const float*)d_in[12];
  const float* Wg  = (const float*)d_in[13];
  const float* a_src = (const float*)d_in[14];
  const float* a_dst = (const float*)d_in[15];
  const float* pw = (const float*)d_in[16];
  const float* pb = (const float*)d_in[17];
  const float* ow1 = (const float*)d_in[18];
  const float* ob1 = (const float*)d_in[19];
  const float* ow2 = (const float*)d_in[20];
  const float* ob2 = (const float*)d_in[21];
  const float* alpha = (const float*)d_in[22];
  const float* beta  = (const float*)d_in[23];
  float* out = (float*)d_out;

  float* ws = (float*)d_ws;
  float* hA = ws;
  float* hB = hA + (size_t)B_*N_*F_;
  short* WhT_hi = (short*)(hB + (size_t)B_*N_*F_);
  short* WhT_lo = WhT_hi + (size_t)B_*H_*F_*N_;   // region kept reserved (unused)
  float* hp = (float*)(WhT_lo + (size_t)B_*H_*F_*N_);
  float* sA = hp + (size_t)B_*H_*N_*F_;
  float* tA = sA + (size_t)B_*H_*N_;
  unsigned* maskT = (unsigned*)(tA + (size_t)B_*H_*N_);
  float* w1m = (float*)(maskT + (size_t)B_*64*N_);
  float* s1ws = hp;   // dead until first attn

  int BN = B_*N_;
  w1m_kernel<<<385, 192, 0, stream>>>(mw1, gw1, w1m);
  mask_kernel<<<B_*64, 256, 0, stream>>>(adj, maskT);
  mlp1_kernel<<<BN/8, 256, 0, stream>>>(deltas, evt, w1m, mb1, gb1, s1ws);
  mlp2_kernel<<<BN/8, 256, 0, stream>>>(s1ws, mw2, mb2, mw3, mb3, gw2, gb2, hA);

  // layer 0
  wh_kernel<<<16*32, 256, 0, stream>>>(hA,
      Wg, a_src, a_dst, WhT_hi, sA, tA);
  attn_kernel<<<512, 512, 0, stream>>>(maskT, WhT_hi, sA, tA, hp);
  proj_kernel<<<1024, 256, 0, stream>>>(hp, pw, pb, hB);

  // layer 1 (projection fused with output head)
  wh_kernel<<<16*32, 256, 0, stream>>>(hB,
      Wg + (size_t)H_*F_*F_, a_src + (size_t)H_*F_, a_dst + (size_t)H_*F_,
      WhT_hi, sA, tA);
  attn_kernel<<<512, 512, 0, stream>>>(maskT, WhT_hi, sA, tA, hp);
  proj_out_kernel<<<1024, 256, 0, stream>>>(hp,
      pw + (size_t)H_*F_*F_, pb + (size_t)F_,
      deltas, alpha, beta, ow1, ob1, ow2, ob2, out);
}